// Round 6
// baseline (87.016 us; speedup 1.0000x reference)
//
#include <hip/hip_runtime.h>
#include <math.h>

#define TB   512
#define HH   128      // input H=W
#define OHW  64       // output H=W
#define TR   32       // output rows per tile
#define NT   2        // tiles per plane (64/32)
#define XR   69       // input rows staged: 2*TR+5
#define XC   136      // 128 cols + pad (col offset +4, zeros in pad)
#define N0R  34       // n0 rows incl. 1-halo (out rows r0-1 .. r0+32)
#define N0C  68       // n0 row stride; interior col c at index c+2 (8B-aligned float2)

typedef float f32x2 __attribute__((ext_vector_type(2)));

__device__ __forceinline__ float sigmoidf(float z) {
    return 1.0f / (1.0f + __expf(-z));
}

__global__ __launch_bounds__(TB, 8) void fused_densenet_kernel(
    const float* __restrict__ x,
    const float* __restrict__ maxgate,
    const float* __restrict__ mb,
    const float* __restrict__ pconvs,
    const float* __restrict__ pbs,
    const float* __restrict__ pgates,
    const float* __restrict__ gbs,
    float* __restrict__ out)
{
    __shared__ float xs[XR][XC];       // input slab, zero-padded (37.5 KB)
    __shared__ float n0s[N0R][N0C];    // n0, halo layout: col c -> index c+2 (9.3 KB)

    const int t     = threadIdx.x;
    const int bid   = blockIdx.x;
    const int tile  = bid & (NT - 1);
    const int plane = bid >> 1;        // b*256 + c
    const int c     = plane & 255;
    const int r0    = tile * TR;       // first global output row of tile

    // ---- uniform weights/biases (block-uniform address -> scalar-resident) ----
    // ws rows: 0=maxgate 1=p0 2=p1 3=p2 4=p3 5=gate0 6=gate2(leaf1+node)
    float ws[7][9];
#pragma unroll
    for (int i = 0; i < 9; ++i) {
        ws[0][i] = maxgate[c * 9  + i];
        ws[1][i] = pconvs [c * 36 + i * 4 + 0];
        ws[2][i] = pconvs [c * 36 + i * 4 + 1];
        ws[3][i] = pconvs [c * 36 + i * 4 + 2];
        ws[4][i] = pconvs [c * 36 + i * 4 + 3];
        ws[5][i] = pgates [c * 27 + i * 3 + 0];
        ws[6][i] = pgates [c * 27 + i * 3 + 2];
    }
    const float bmax = mb[c];
    const float bp0 = pbs[c * 4 + 0], bp1 = pbs[c * 4 + 1];
    const float bp2 = pbs[c * 4 + 2], bp3 = pbs[c * 4 + 3];
    const float bg0 = gbs[c * 3 + 0];   // leaf0 gate bias
    const float bg1 = gbs[c * 3 + 1];   // leaf1 gate bias
    const float bg2 = gbs[c * 3 + 2];   // node gate bias

    // ---- global -> LDS: rows [2*r0-3 , 2*r0+65], cols -4..131 (zero pad) ----
    const float* xplane = x + (size_t)plane * (HH * HH);
    const int ir0 = 2 * r0 - 3;
    for (int s = t; s < XR * 34; s += TB) {       // 34 float4 slots per row
        const int rr = s / 34;
        const int qq = s - rr * 34;
        float4 v = make_float4(0.f, 0.f, 0.f, 0.f);
        const int ir = ir0 + rr;
        if (qq >= 1 && qq <= 32 && (unsigned)ir < (unsigned)HH) {
            v = *reinterpret_cast<const float4*>(xplane + ir * HH + (qq - 1) * 4);
        }
        *reinterpret_cast<float4*>(&xs[rr][qq * 4]) = v;   // 16B-aligned
    }
    __syncthreads();

    // ---- halo ring of n0 (rows 0 & 33 full, side cols idx 1 & 66) ----
    if (t < 196) {
        int lrr, li;
        if (t < 66)        { lrr = 0;        li = t + 1;       }
        else if (t < 132)  { lrr = N0R - 1;  li = t - 66 + 1;  }
        else { const int i = t - 132; lrr = 1 + (i >> 1); li = (i & 1) ? 66 : 1; }
        const int gr = r0 - 1 + lrr;   // global output row of this n0 entry
        const int gc = li - 2;         // global output col
        float n0v = 0.f;               // stage-2 conv zero-pads n0 at image edge
        if ((unsigned)gr < (unsigned)OHW && (unsigned)gc < (unsigned)OHW) {
            float ag = 0.f, a0 = 0.f, a1 = 0.f;
#pragma unroll
            for (int dr = 0; dr < 3; ++dr)
#pragma unroll
                for (int dc = 0; dc < 3; ++dc) {
                    const float v = xs[2 * lrr + dr][2 * gc + dc + 3];
                    const int i = dr * 3 + dc;
                    ag += v * ws[5][i];
                    a0 += v * ws[1][i];
                    a1 += v * ws[2][i];
                }
            const float sg = sigmoidf(ag + bg0);
            n0v = sg * (a0 + bp0) + (1.f - sg) * (a1 + bp1);
        }
        n0s[lrr][li] = n0v;
    }

    // ---- stage 1: 2 cols x 1 row per micro-step, b32+b128 window reads ----
    const int p  = t & 31;            // col pair: out cols {2p, 2p+1}
    const int g0 = t >> 5;            // row group 0..15; rows g0, g0+16
    float out1[2][2], n1v[2][2];

#pragma unroll
    for (int k = 0; k < 2; ++k) {
        const int lr = g0 + 16 * k;   // local output row
        const int gr = r0 + lr;

        float a[7][2];
#pragma unroll
        for (int ci = 0; ci < 7; ++ci) { a[ci][0] = 0.f; a[ci][1] = 0.f; }
        float mp0 = -INFINITY, mp1 = -INFINITY;

#pragma unroll
        for (int dr = 0; dr < 3; ++dr) {
            const int xr = 2 * lr + 2 + dr;
            const float  v0 = xs[xr][4 * p + 3];                              // col 4p-1
            const float4 vv = *reinterpret_cast<const float4*>(&xs[xr][4 * p + 4]);

            // maxpool (pad = -inf): left col invalid at p==0, row invalid at gr==0,dr==0
            const bool rowok = (gr > 0) | (dr > 0);
            const float h0 = fmaxf(fmaxf((p > 0) ? v0 : -INFINITY, vv.x), vv.y);
            const float h1 = fmaxf(fmaxf(vv.y, vv.z), vv.w);
            mp0 = fmaxf(mp0, rowok ? h0 : -INFINITY);
            mp1 = fmaxf(mp1, rowok ? h1 : -INFINITY);

            // convs: zero pad already in xs
#pragma unroll
            for (int ci = 0; ci < 7; ++ci) {
                a[ci][0] += v0   * ws[ci][3 * dr] + vv.x * ws[ci][3 * dr + 1] + vv.y * ws[ci][3 * dr + 2];
                a[ci][1] += vv.y * ws[ci][3 * dr] + vv.z * ws[ci][3 * dr + 1] + vv.w * ws[ci][3 * dr + 2];
            }
        }

        const float sg0a = sigmoidf(a[5][0] + bg0);
        const float sg0b = sigmoidf(a[5][1] + bg0);
        const float n0a = sg0a * (a[1][0] + bp0) + (1.f - sg0a) * (a[2][0] + bp1);
        const float n0b = sg0b * (a[1][1] + bp0) + (1.f - sg0b) * (a[2][1] + bp1);
        *reinterpret_cast<f32x2*>(&n0s[lr + 1][2 * p + 2]) = (f32x2){ n0a, n0b };

        const float sg1a = sigmoidf(a[6][0] + bg1);    // leaf1 gate: bias gbs[:,1]
        const float sg1b = sigmoidf(a[6][1] + bg1);
        n1v[k][0] = sg1a * (a[3][0] + bp2) + (1.f - sg1a) * (a[4][0] + bp3);
        n1v[k][1] = sg1b * (a[3][1] + bp2) + (1.f - sg1b) * (a[4][1] + bp3);
        out1[k][0] = mp0 * (a[0][0] + bmax);
        out1[k][1] = mp1 * (a[0][1] + bmax);
    }
    __syncthreads();

    // ---- stage 2: node gate conv on n0 (stride 1, pad 1) + combine + store ----
    float* oplane = out + (size_t)plane * (OHW * OHW);
#pragma unroll
    for (int k = 0; k < 2; ++k) {
        const int lr = g0 + 16 * k;
        float ag0 = 0.f, ag1 = 0.f;
        float n0c0 = 0.f, n0c1 = 0.f;
#pragma unroll
        for (int dr = 0; dr < 3; ++dr) {
            const float  e0  = n0s[lr + dr][2 * p + 1];
            const f32x2  mid = *reinterpret_cast<const f32x2*>(&n0s[lr + dr][2 * p + 2]);
            const float  e3  = n0s[lr + dr][2 * p + 4];
            ag0 += e0     * ws[6][3 * dr] + mid.x * ws[6][3 * dr + 1] + mid.y * ws[6][3 * dr + 2];
            ag1 += mid.x  * ws[6][3 * dr] + mid.y * ws[6][3 * dr + 1] + e3    * ws[6][3 * dr + 2];
            if (dr == 1) { n0c0 = mid.x; n0c1 = mid.y; }
        }
        const float ga = sigmoidf(ag0 + bg2);          // node gate: bias gbs[:,2]
        const float gb = sigmoidf(ag1 + bg2);
        const float r0v = out1[k][0] + n0c0 * ga + n1v[k][0] * (1.f - ga);
        const float r1v = out1[k][1] + n0c1 * gb + n1v[k][1] * (1.f - gb);
        __builtin_nontemporal_store((f32x2){ r0v, r1v },
            reinterpret_cast<f32x2*>(&oplane[(r0 + lr) * OHW + 2 * p]));
    }
}

extern "C" void kernel_launch(void* const* d_in, const int* in_sizes, int n_in,
                              void* d_out, int out_size, void* d_ws, size_t ws_size,
                              hipStream_t stream) {
    const float* x       = (const float*)d_in[0];
    const float* maxgate = (const float*)d_in[1];
    const float* mb      = (const float*)d_in[2];
    const float* pconvs  = (const float*)d_in[3];
    const float* pbs     = (const float*)d_in[4];
    const float* pgates  = (const float*)d_in[5];
    const float* gbs     = (const float*)d_in[6];
    float* out           = (float*)d_out;

    const int blocks = 16 * 256 * NT;   // B * C * tiles-per-plane
    fused_densenet_kernel<<<blocks, TB, 0, stream>>>(
        x, maxgate, mb, pconvs, pbs, pgates, gbs, out);
}